// Round 8
// baseline (3343.188 us; speedup 1.0000x reference)
//
#include <hip/hip_runtime.h>
#include <math.h>

#define NPIX (1024*1024)
#define MC 960
#define MAP_ELEMS (MC*MC)

/* ws layout (floats):
   [0, 20000)      fp maps: ch0 fp_map then ch1 fp_exp, each 100x100 row-major
   [20000, 20008)  params: cth, sth, sx, sy, ca, sa
   [20032, ...)    xbin: 1 MB of per-pixel x-slab keys (uint8)
*/

__device__ __forceinline__ void compute_pos(int i, int j, float d,
                                            float ca, float sa, float* pos) {
    /* point cloud (f = 512 exactly in f32) */
    float X = ((float)j - 511.5f) * d / 512.0f;
    float Z = ((float)(1023 - i) - 511.5f) * d / 512.0f;
    float Y = d;
    /* Rx(elev), +AGENT_H on z */
    float x1 = X;
    float y1 = ca*Y - sa*Z;
    float z1 = (sa*Y + ca*Z) + 88.0f;
    /* Rz(-pi/2) + SHIFT_X */
    const float CB = 6.123233995736766e-17f;
    float x2 = (CB*x1 + y1) + 250.0f;
    float y2 = (-x1) + CB*y1;
    float z2 = z1;
    /* coords -> splat positions, matching reference op order */
    float cx = (x2/5.0f - 50.0f)/100.0f*2.0f;
    float cy = (y2/5.0f - 50.0f)/100.0f*2.0f;
    float cz = (z2/5.0f - 32.0f)/80.0f*2.0f;
    pos[0] = cx*50.0f + 50.0f;
    pos[1] = cy*50.0f + 50.0f;
    pos[2] = cz*40.0f + 40.0f;
}

__global__ void pose_kernel(const float* __restrict__ pose_obs,
                            const float* __restrict__ poses_last,
                            const int* __restrict__ elev,
                            float* __restrict__ params,
                            float* __restrict__ out_cur) {
    float th = poses_last[2] / 57.29577951308232f;
    float s = sinf(th), c = cosf(th);
    float ny = (poses_last[1] + pose_obs[0]*s) + pose_obs[1]*c;
    float nx = (poses_last[0] + pose_obs[0]*c) - pose_obs[1]*s;
    float nt = poses_last[2] + pose_obs[2]*57.29577951308232f;
    nt = fmodf(nt - 180.0f, 360.0f) + 180.0f;
    nt = fmodf(nt + 180.0f, 360.0f) - 180.0f;
    out_cur[0] = nx; out_cur[1] = ny; out_cur[2] = nt;
    out_cur[3] = nx; out_cur[4] = ny; out_cur[5] = nt;

    float spx = -((nx*100.0f)/5.0f - 480.0f)/480.0f;
    float spy = -((ny*100.0f)/5.0f - 480.0f)/480.0f;
    float tdeg = nt - 180.0f;
    float trad = (tdeg * (float)M_PI) / 180.0f;
    params[0] = cosf(trad);
    params[1] = sinf(trad);
    params[2] = spy;   /* x-offset of trans grid (st[:,0] = sp reversed) */
    params[3] = spx;   /* y-offset */
    double a = (double)elev[0] * (M_PI/180.0);
    params[4] = (float)cos(a);
    params[5] = (float)sin(a);
}

/* pass A: per-pixel x-slab key (depends only on depth + pixel coords) */
__global__ void binkey_kernel(const float* __restrict__ depth,
                              const float* __restrict__ params,
                              unsigned char* __restrict__ xbin) {
    int n = blockIdx.x*blockDim.x + threadIdx.x;
    if (n >= NPIX) return;
    int i = n >> 10, j = n & 1023;
    float pos[3];
    compute_pos(i, j, depth[n], params[4], params[5], pos);
    float fl = floorf(pos[0]);
    xbin[n] = (fl >= 0.0f && fl <= 99.0f) ? (unsigned char)(int)fl : 0xFF;
}

__device__ __forceinline__ bool has_byte(unsigned long long v, unsigned int b) {
    unsigned long long x = v ^ (0x0101010101010101ULL * (unsigned long long)b);
    return ((x - 0x0101010101010101ULL) & ~x & 0x8080808080808080ULL) != 0ULL;
}

/* pass B: block b accumulates x-slab b in LDS (2 wave-replicas), then fused
   round/sum/clip -> fp columns. No global atomics anywhere. */
__global__ void slab_kernel(const float* __restrict__ depth,
                            const float* __restrict__ feat,
                            const unsigned char* __restrict__ xbin,
                            const float* __restrict__ params,
                            float* __restrict__ fp,
                            float* __restrict__ out_fpmap) {
    __shared__ float slab[2][8000];   /* 64 KB */
    int b = blockIdx.x;               /* x-cell owned: 1..99; b==0 writes zeros */
    int tid = threadIdx.x;

    if (b == 0) {
        if (tid < 100) {
            int y = tid;
            int t_out = (99 - y)*100 + 0;
            fp[t_out] = 0.0f;
            fp[10000 + t_out] = 0.0f;
            out_fpmap[t_out] = 0.0f;
        }
        return;
    }

    for (int idx = tid; idx < 16000; idx += 256) ((float*)slab)[idx] = 0.0f;
    __syncthreads();

    float ca = params[4], sa = params[5];
    int rep = (tid >> 6) & 1;
    float* sl = slab[rep];
    unsigned int bm1 = (unsigned int)(b - 1), bb = (unsigned int)b;
    const unsigned long long* xb64 = (const unsigned long long*)xbin;

    for (int idx = tid; idx < NPIX/8; idx += 256) {
        unsigned long long v = xb64[idx];
        if (!(has_byte(v, bm1) | has_byte(v, bb))) continue;
        for (int by = 0; by < 8; ++by) {
            unsigned int key = (unsigned int)((v >> (8*by)) & 0xFFULL);
            if (key != bm1 && key != bb) continue;
            int n = (idx << 3) + by;
            int i = n >> 10, j = n & 1023;
            float d = depth[n];
            float pos[3];
            compute_pos(i, j, d, ca, sa, pos);
            /* x-corner: target cell is b (byte-driven; robust to 1-ulp drift) */
            float wx = 1.0f - fabsf(pos[0] - (float)b);
            float fly = floorf(pos[1]);
            float flz = floorf(pos[2]);
            float wyv[2]; int iyv[2];
#pragma unroll
            for (int o = 0; o < 2; ++o) {
                float p = fly + (float)o;
                bool s = (p > 0.0f) && (p < 100.0f);
                wyv[o] = s ? (1.0f - fabsf(pos[1] - p)) : 0.0f;
                iyv[o] = s ? (int)p : 0;
            }
            float wzv[2]; int izv[2];
#pragma unroll
            for (int o = 0; o < 2; ++o) {
                float p = flz + (float)o;
                bool s = (p > 0.0f) && (p < 80.0f);
                wzv[o] = s ? (1.0f - fabsf(pos[2] - p)) : 0.0f;
                izv[o] = s ? (int)p : 0;
            }
            float fv = feat[n];
#pragma unroll
            for (int o1 = 0; o1 < 2; ++o1)
#pragma unroll
            for (int o2 = 0; o2 < 2; ++o2) {
                float w = (wx*wyv[o1])*wzv[o2];
                if (w != 0.0f) atomicAdd(&sl[iyv[o1]*80 + izv[o2]], fv*w);
            }
        }
    }
    __syncthreads();

    /* fused reduce: per y-column round + sum + clip, write fp for cc=b */
    if (tid < 100) {
        int y = tid;
        float s_all = 0.0f, s_mid = 0.0f;
        for (int k = 0; k < 80; ++k) {
            float tot = slab[0][y*80 + k] + slab[1][y*80 + k];
            float vv = rintf(tot);        /* jnp.round = half-to-even */
            s_all += vv;
            if (k >= 13 && k < 25) s_mid += vv;
        }
        float fpm = fminf(fmaxf(s_mid, 0.0f), 1.0f);
        float fpe = fminf(fmaxf(s_all, 0.0f), 1.0f);
        int t_out = (99 - y)*100 + b;
        fp[t_out] = fpm;
        fp[10000 + t_out] = fpe;
        out_fpmap[t_out] = fpm;
    }
}

__device__ __forceinline__ float av_at(const float* __restrict__ fp, int c, int yy, int xx) {
    if (yy >= 380 && yy < 480 && xx >= 430 && xx < 530)
        return fp[c*10000 + (yy-380)*100 + (xx-430)];
    return 0.0f;
}

__device__ __forceinline__ float samp_av(const float* __restrict__ fp, int c,
                                         float ixf, float iyf) {
    if (ixf >= 0.0f && ixf < 960.0f && iyf >= 0.0f && iyf < 960.0f)
        return av_at(fp, c, (int)iyf, (int)ixf);
    return 0.0f;
}

__device__ float rot_sample(const float* __restrict__ fp, int c, int ii, int jj,
                            float cth, float sth) {
    float gxx = ((float)jj*2.0f + 1.0f)/960.0f - 1.0f;
    float gyy = ((float)ii*2.0f + 1.0f)/960.0f - 1.0f;
    float rx = cth*gxx + (-sth)*gyy;
    float ry = sth*gxx + cth*gyy;
    float x = (rx + 1.0f)*0.5f*959.0f;
    float y = (ry + 1.0f)*0.5f*959.0f;
    float x0 = floorf(x), y0 = floorf(y);
    float wx = x - x0, wy = y - y0;
    float acc;
    acc =       samp_av(fp,c,x0,     y0     )*(1.0f-wx)*(1.0f-wy);
    acc = acc + samp_av(fp,c,x0+1.0f,y0     )*wx       *(1.0f-wy);
    acc = acc + samp_av(fp,c,x0,     y0+1.0f)*(1.0f-wx)*wy;
    acc = acc + samp_av(fp,c,x0+1.0f,y0+1.0f)*wx       *wy;
    return acc;
}

__device__ __forceinline__ float samp_rot(const float* __restrict__ fp, int c,
                                          float ixf, float iyf, float cth, float sth) {
    if (ixf >= 0.0f && ixf < 960.0f && iyf >= 0.0f && iyf < 960.0f)
        return rot_sample(fp, c, (int)iyf, (int)ixf, cth, sth);
    return 0.0f;
}

__global__ void trans_kernel(const float* __restrict__ fp,
                             const float* __restrict__ params,
                             const float* __restrict__ maps_last,
                             float* __restrict__ out_map) {
    int t = blockIdx.x*blockDim.x + threadIdx.x;
    if (t >= 2*MAP_ELEMS) return;
    int c = t / MAP_ELEMS;
    int rem = t - c*MAP_ELEMS;
    int i = rem / MC, j = rem - (rem / MC)*MC;
    float cth = params[0], sth = params[1], sx = params[2], sy = params[3];

    float gx = ((float)j*2.0f + 1.0f)/960.0f - 1.0f;
    float gy = ((float)i*2.0f + 1.0f)/960.0f - 1.0f;
    float tx = gx + sx;
    float ty = gy + sy;
    float x = (tx + 1.0f)*0.5f*959.0f;
    float y = (ty + 1.0f)*0.5f*959.0f;

    /* early-out: rigid map of the continuous sample point; if it is more than
       ~2.5 px (margin 4+) outside the active 100x100 window in rot space, all
       16 texels of the two-stage sampling are provably zero. */
    float gxc = (2.0f*x + 1.0f)/960.0f - 1.0f;
    float gyc = (2.0f*y + 1.0f)/960.0f - 1.0f;
    float rxc = cth*gxc - sth*gyc;
    float ryc = sth*gxc + cth*gyc;
    float pxc = (rxc + 1.0f)*0.5f*959.0f;
    float pyc = (ryc + 1.0f)*0.5f*959.0f;
    bool heavy = (pxc >= 425.0f) && (pxc <= 535.0f) &&
                 (pyc >= 375.0f) && (pyc <= 485.0f);

    float acc = 0.0f;
    if (heavy) {
        float x0 = floorf(x), y0 = floorf(y);
        float wx = x - x0, wy = y - y0;
        acc =       samp_rot(fp,c,x0,     y0,     cth,sth)*(1.0f-wx)*(1.0f-wy);
        acc = acc + samp_rot(fp,c,x0+1.0f,y0,     cth,sth)*wx       *(1.0f-wy);
        acc = acc + samp_rot(fp,c,x0,     y0+1.0f,cth,sth)*(1.0f-wx)*wy;
        acc = acc + samp_rot(fp,c,x0+1.0f,y0+1.0f,cth,sth)*wx       *wy;
    }
    out_map[t] = fmaxf(maps_last[t], acc);
}

extern "C" void kernel_launch(void* const* d_in, const int* in_sizes, int n_in,
                              void* d_out, int out_size, void* d_ws, size_t ws_size,
                              hipStream_t stream) {
    const float* depth      = (const float*)d_in[0];
    const float* pose_obs   = (const float*)d_in[1];
    const float* maps_last  = (const float*)d_in[2];
    const float* poses_last = (const float*)d_in[3];
    const float* feat       = (const float*)d_in[4];
    const int*   elev       = (const int*)d_in[5];
    float* out = (float*)d_out;

    float* fp     = (float*)d_ws;                     /* 20000 floats */
    float* params = fp + 20000;                       /* 8 floats     */
    unsigned char* xbin = (unsigned char*)(fp + 20032); /* 1 MB, 8B-aligned */

    pose_kernel<<<1, 1, 0, stream>>>(pose_obs, poses_last, elev, params,
                                     out + 10000 + 2*MAP_ELEMS);
    binkey_kernel<<<(NPIX+255)/256, 256, 0, stream>>>(depth, params, xbin);
    slab_kernel<<<100, 256, 0, stream>>>(depth, feat, xbin, params, fp, out);
    trans_kernel<<<(2*MAP_ELEMS+255)/256, 256, 0, stream>>>(fp, params, maps_last,
                                                            out + 10000);
}

// Round 9
// 300.465 us; speedup vs baseline: 11.1267x; 11.1267x over previous
//
#include <hip/hip_runtime.h>
#include <math.h>

#define VRX 100
#define NZ 80
#define GRID_CELLS (VRX*VRX*NZ)   /* 800000 */
#define NPIX (1024*1024)
#define MC 960
#define MAP_ELEMS (MC*MC)
#define RMAX 8

/* ws layout (floats):
   [0, 20000)      fp maps: ch0 fp_map then ch1 fp_exp, each 100x100 row-major
   [20000, 20008)  params: cth, sth, sx, sy, ca, sa
   [20032, ...)    R replicas of the 800000-float voxel grid (16B aligned)
*/

__global__ void pose_kernel(const float* __restrict__ pose_obs,
                            const float* __restrict__ poses_last,
                            const int* __restrict__ elev,
                            float* __restrict__ params,
                            float* __restrict__ out_cur) {
    float th = poses_last[2] / 57.29577951308232f;
    float s = sinf(th), c = cosf(th);
    float ny = (poses_last[1] + pose_obs[0]*s) + pose_obs[1]*c;
    float nx = (poses_last[0] + pose_obs[0]*c) - pose_obs[1]*s;
    float nt = poses_last[2] + pose_obs[2]*57.29577951308232f;
    nt = fmodf(nt - 180.0f, 360.0f) + 180.0f;
    nt = fmodf(nt + 180.0f, 360.0f) - 180.0f;
    out_cur[0] = nx; out_cur[1] = ny; out_cur[2] = nt;
    out_cur[3] = nx; out_cur[4] = ny; out_cur[5] = nt;

    float spx = -((nx*100.0f)/5.0f - 480.0f)/480.0f;
    float spy = -((ny*100.0f)/5.0f - 480.0f)/480.0f;
    float tdeg = nt - 180.0f;
    float trad = (tdeg * (float)M_PI) / 180.0f;
    params[0] = cosf(trad);
    params[1] = sinf(trad);
    params[2] = spy;   /* x-offset of trans grid (st[:,0] = sp reversed) */
    params[3] = spx;   /* y-offset */
    double a = (double)elev[0] * (M_PI/180.0);
    params[4] = (float)cos(a);
    params[5] = (float)sin(a);
}

__global__ void splat_kernel(const float* __restrict__ depth,
                             const float* __restrict__ feat,
                             const float* __restrict__ params,
                             float* __restrict__ grids, int rmask) {
    int n = blockIdx.x*blockDim.x + threadIdx.x;
    if (n >= NPIX) return;
    float* grid = grids + (size_t)(blockIdx.x & rmask) * GRID_CELLS;
    int i = n >> 10, j = n & 1023;
    float d = depth[n];
    float ca = params[4], sa = params[5];

    /* point cloud (f = 512 exactly in f32) */
    float X = ((float)j - 511.5f) * d / 512.0f;
    float Z = ((float)(1023 - i) - 511.5f) * d / 512.0f;
    float Y = d;

    /* Rx(elev), +AGENT_H on z */
    float x1 = X;
    float y1 = ca*Y - sa*Z;
    float z1 = (sa*Y + ca*Z) + 88.0f;

    /* Rz(-pi/2): cb = cos(-pi/2) as f32, -sb = 1, sb = -1 */
    const float CB = 6.123233995736766e-17f;
    float x2 = (CB*x1 + y1) + 250.0f;   /* + SHIFT_X */
    float y2 = (-x1) + CB*y1;
    float z2 = z1;

    /* coords -> splat positions, matching reference op order */
    float cx = (x2/5.0f - 50.0f)/100.0f*2.0f;
    float cy = (y2/5.0f - 50.0f)/100.0f*2.0f;
    float cz = (z2/5.0f - 32.0f)/80.0f*2.0f;
    float posv[3];
    posv[0] = cx*50.0f + 50.0f;
    posv[1] = cy*50.0f + 50.0f;
    posv[2] = cz*40.0f + 40.0f;
    const float dimv[3] = {100.0f, 100.0f, 80.0f};

    int   pi[3][2];
    float wv[3][2];
#pragma unroll
    for (int dd = 0; dd < 3; ++dd) {
        float fl = floorf(posv[dd]);
#pragma unroll
        for (int o = 0; o < 2; ++o) {
            float p = fl + (float)o;
            bool safe = (p > 0.0f) && (p < dimv[dd]);
            wv[dd][o] = safe ? (1.0f - fabsf(posv[dd] - p)) : 0.0f;
            pi[dd][o] = safe ? (int)p : 0;
        }
    }
    float fv = feat[n];
#pragma unroll
    for (int c0 = 0; c0 < 2; ++c0)
#pragma unroll
    for (int c1 = 0; c1 < 2; ++c1)
#pragma unroll
    for (int c2 = 0; c2 < 2; ++c2) {
        float w = (wv[0][c0]*wv[1][c1])*wv[2][c2];
        if (w != 0.0f) {
            int idx = (pi[0][c0]*100 + pi[1][c1])*80 + pi[2][c2];
            atomicAdd(&grid[idx], fv*w);
        }
    }
}

/* coalesced in-place sum of R replicas into replica 0 */
__global__ void repsum_kernel(float* __restrict__ grids, int R) {
    int t = blockIdx.x*blockDim.x + threadIdx.x;
    if (t >= GRID_CELLS/4) return;
    float4* g4 = (float4*)grids;
    float4 acc = g4[t];
    for (int rep = 1; rep < R; ++rep) {
        float4 v = g4[(size_t)rep*(GRID_CELLS/4) + t];
        acc.x += v.x; acc.y += v.y; acc.z += v.z; acc.w += v.w;
    }
    g4[t] = acc;
}

/* 4 threads per output column; float4 z-loads; 4-lane shuffle combine */
__global__ void reduce_kernel(const float* __restrict__ grid,
                              float* __restrict__ fp,
                              float* __restrict__ out_fpmap) {
    int tq = blockIdx.x*blockDim.x + threadIdx.x;
    if (tq >= 40000) return;
    int col = tq >> 2, q = tq & 3;
    int r = col / 100, cc = col % 100;
    int base = (cc*100 + (99 - r))*80 + q*20;
    const float4* g4 = (const float4*)(grid + base);
    float s_all = 0.0f, s_mid = 0.0f;
#pragma unroll
    for (int v4 = 0; v4 < 5; ++v4) {
        float4 vv = g4[v4];
        float vals[4] = {vv.x, vv.y, vv.z, vv.w};
#pragma unroll
        for (int e = 0; e < 4; ++e) {
            float rv = rintf(vals[e]);    /* jnp.round = half-to-even */
            s_all += rv;
            int k = q*20 + v4*4 + e;
            if (k >= 13 && k < 25) s_mid += rv;
        }
    }
    /* integer-valued f32 partials: exact under any summation order */
    s_all += __shfl_xor(s_all, 1); s_all += __shfl_xor(s_all, 2);
    s_mid += __shfl_xor(s_mid, 1); s_mid += __shfl_xor(s_mid, 2);
    if (q == 0) {
        float fpm = fminf(fmaxf(s_mid, 0.0f), 1.0f);
        float fpe = fminf(fmaxf(s_all, 0.0f), 1.0f);
        fp[col] = fpm;
        fp[10000 + col] = fpe;
        out_fpmap[col] = fpm;
    }
}

__device__ __forceinline__ float av_at(const float* __restrict__ fp, int c, int yy, int xx) {
    if (yy >= 380 && yy < 480 && xx >= 430 && xx < 530)
        return fp[c*10000 + (yy-380)*100 + (xx-430)];
    return 0.0f;
}

__device__ __forceinline__ float samp_av(const float* __restrict__ fp, int c,
                                         float ixf, float iyf) {
    if (ixf >= 0.0f && ixf < 960.0f && iyf >= 0.0f && iyf < 960.0f)
        return av_at(fp, c, (int)iyf, (int)ixf);
    return 0.0f;
}

__device__ float rot_sample(const float* __restrict__ fp, int c, int ii, int jj,
                            float cth, float sth) {
    float gxx = ((float)jj*2.0f + 1.0f)/960.0f - 1.0f;
    float gyy = ((float)ii*2.0f + 1.0f)/960.0f - 1.0f;
    float rx = cth*gxx + (-sth)*gyy;
    float ry = sth*gxx + cth*gyy;
    float x = (rx + 1.0f)*0.5f*959.0f;
    float y = (ry + 1.0f)*0.5f*959.0f;
    float x0 = floorf(x), y0 = floorf(y);
    float wx = x - x0, wy = y - y0;
    float acc;
    acc =       samp_av(fp,c,x0,     y0     )*(1.0f-wx)*(1.0f-wy);
    acc = acc + samp_av(fp,c,x0+1.0f,y0     )*wx       *(1.0f-wy);
    acc = acc + samp_av(fp,c,x0,     y0+1.0f)*(1.0f-wx)*wy;
    acc = acc + samp_av(fp,c,x0+1.0f,y0+1.0f)*wx       *wy;
    return acc;
}

__device__ __forceinline__ float samp_rot(const float* __restrict__ fp, int c,
                                          float ixf, float iyf, float cth, float sth) {
    if (ixf >= 0.0f && ixf < 960.0f && iyf >= 0.0f && iyf < 960.0f)
        return rot_sample(fp, c, (int)iyf, (int)ixf, cth, sth);
    return 0.0f;
}

__global__ void trans_kernel(const float* __restrict__ fp,
                             const float* __restrict__ params,
                             const float* __restrict__ maps_last,
                             float* __restrict__ out_map) {
    int t = blockIdx.x*blockDim.x + threadIdx.x;
    if (t >= 2*MAP_ELEMS) return;
    int c = t / MAP_ELEMS;
    int rem = t - c*MAP_ELEMS;
    int i = rem / MC, j = rem - (rem / MC)*MC;
    float cth = params[0], sth = params[1], sx = params[2], sy = params[3];

    float gx = ((float)j*2.0f + 1.0f)/960.0f - 1.0f;
    float gy = ((float)i*2.0f + 1.0f)/960.0f - 1.0f;
    float tx = gx + sx;
    float ty = gy + sy;
    float x = (tx + 1.0f)*0.5f*959.0f;
    float y = (ty + 1.0f)*0.5f*959.0f;

    /* early-out: rigid map of the continuous sample point; outside a ~4.4 px
       margin of the active 100x100 window all 16 texels are provably zero. */
    float gxc = (2.0f*x + 1.0f)/960.0f - 1.0f;
    float gyc = (2.0f*y + 1.0f)/960.0f - 1.0f;
    float rxc = cth*gxc - sth*gyc;
    float ryc = sth*gxc + cth*gyc;
    float pxc = (rxc + 1.0f)*0.5f*959.0f;
    float pyc = (ryc + 1.0f)*0.5f*959.0f;
    bool heavy = (pxc >= 425.0f) && (pxc <= 535.0f) &&
                 (pyc >= 375.0f) && (pyc <= 485.0f);

    float acc = 0.0f;
    if (heavy) {
        float x0 = floorf(x), y0 = floorf(y);
        float wx = x - x0, wy = y - y0;
        acc =       samp_rot(fp,c,x0,     y0,     cth,sth)*(1.0f-wx)*(1.0f-wy);
        acc = acc + samp_rot(fp,c,x0+1.0f,y0,     cth,sth)*wx       *(1.0f-wy);
        acc = acc + samp_rot(fp,c,x0,     y0+1.0f,cth,sth)*(1.0f-wx)*wy;
        acc = acc + samp_rot(fp,c,x0+1.0f,y0+1.0f,cth,sth)*wx       *wy;
    }
    out_map[t] = fmaxf(maps_last[t], acc);
}

extern "C" void kernel_launch(void* const* d_in, const int* in_sizes, int n_in,
                              void* d_out, int out_size, void* d_ws, size_t ws_size,
                              hipStream_t stream) {
    const float* depth      = (const float*)d_in[0];
    const float* pose_obs   = (const float*)d_in[1];
    const float* maps_last  = (const float*)d_in[2];
    const float* poses_last = (const float*)d_in[3];
    const float* feat       = (const float*)d_in[4];
    const int*   elev       = (const int*)d_in[5];
    float* out = (float*)d_out;

    float* fp     = (float*)d_ws;        /* 20000 floats */
    float* params = fp + 20000;          /* 8 floats     */
    float* grids  = fp + 20032;          /* R * 800000, 16B aligned */

    /* largest power-of-2 replica count that fits the workspace (>=1) */
    size_t avail = ws_size / sizeof(float);
    int R = 1;
    while (R < RMAX && (size_t)20032 + (size_t)GRID_CELLS*(size_t)(R*2) <= avail)
        R *= 2;

    hipMemsetAsync(grids, 0, (size_t)R*GRID_CELLS*sizeof(float), stream);
    pose_kernel<<<1, 1, 0, stream>>>(pose_obs, poses_last, elev, params,
                                     out + 10000 + 2*MAP_ELEMS);
    splat_kernel<<<(NPIX+255)/256, 256, 0, stream>>>(depth, feat, params, grids, R-1);
    if (R > 1)
        repsum_kernel<<<(GRID_CELLS/4+255)/256, 256, 0, stream>>>(grids, R);
    reduce_kernel<<<(40000+255)/256, 256, 0, stream>>>(grids, fp, out);
    trans_kernel<<<(2*MAP_ELEMS+255)/256, 256, 0, stream>>>(fp, params, maps_last,
                                                            out + 10000);
}